// Round 1
// baseline (2901.359 us; speedup 1.0000x reference)
//
#include <hip/hip_runtime.h>
#include <hip/hip_bf16.h>
#include <math.h>

// Problem constants
#define BB 2
#define SS 2048
#define HID 2048
#define NH 16
#define NKV 4
#define HD 128
#define MTOT (BB * SS)          // 4096 rows
#define KDIM HID                // 2048

// ---------------------------------------------------------------------------
// Generic fp32 tiled GEMM body: C[m0:m0+128, n0:n0+128] = A @ W (+ bias)
// A: M x K row-major, W: K x N row-major. 256 threads, 8x8 micro-tile.
// ---------------------------------------------------------------------------
__device__ __forceinline__ void gemm_tile_body(
    const float* __restrict__ A, const float* __restrict__ W,
    const float* __restrict__ bias, float* __restrict__ C,
    int N, int Kdim, int m0, int n0, int tid)
{
    __shared__ float As[16][128 + 4];   // transposed: As[k][m]
    __shared__ float Bs[16][128];

    const int tx = tid % 16;            // output col group
    const int ty = tid / 16;            // output row group
    const int a_m = tid / 4;            // 0..63
    const int a_k = (tid % 4) * 4;      // 0,4,8,12
    const int b_k = tid / 32;           // 0..7
    const int b_n = (tid % 32) * 4;     // 0..124

    float acc[8][8];
    #pragma unroll
    for (int i = 0; i < 8; ++i)
        #pragma unroll
        for (int j = 0; j < 8; ++j) acc[i][j] = 0.f;

    for (int k0 = 0; k0 < Kdim; k0 += 16) {
        // load A tile (128 rows x 16 cols), store transposed
        #pragma unroll
        for (int p = 0; p < 2; ++p) {
            int m = a_m + p * 64;
            float4 v = *reinterpret_cast<const float4*>(
                &A[(size_t)(m0 + m) * Kdim + k0 + a_k]);
            As[a_k + 0][m] = v.x;
            As[a_k + 1][m] = v.y;
            As[a_k + 2][m] = v.z;
            As[a_k + 3][m] = v.w;
        }
        // load B tile (16 rows x 128 cols)
        #pragma unroll
        for (int p = 0; p < 2; ++p) {
            int kk = b_k + p * 8;
            *reinterpret_cast<float4*>(&Bs[kk][b_n]) =
                *reinterpret_cast<const float4*>(
                    &W[(size_t)(k0 + kk) * N + n0 + b_n]);
        }
        __syncthreads();
        #pragma unroll
        for (int kk = 0; kk < 16; ++kk) {
            float a[8], b[8];
            *reinterpret_cast<float4*>(&a[0]) =
                *reinterpret_cast<float4*>(&As[kk][ty * 8]);
            *reinterpret_cast<float4*>(&a[4]) =
                *reinterpret_cast<float4*>(&As[kk][ty * 8 + 4]);
            *reinterpret_cast<float4*>(&b[0]) =
                *reinterpret_cast<float4*>(&Bs[kk][tx * 8]);
            *reinterpret_cast<float4*>(&b[4]) =
                *reinterpret_cast<float4*>(&Bs[kk][tx * 8 + 4]);
            #pragma unroll
            for (int i = 0; i < 8; ++i)
                #pragma unroll
                for (int j = 0; j < 8; ++j)
                    acc[i][j] = fmaf(a[i], b[j], acc[i][j]);
        }
        __syncthreads();
    }
    // epilogue
    #pragma unroll
    for (int i = 0; i < 8; ++i) {
        int m = m0 + ty * 8 + i;
        #pragma unroll
        for (int j = 0; j < 8; j += 4) {
            int n = n0 + tx * 8 + j;
            float4 v;
            v.x = acc[i][j + 0]; v.y = acc[i][j + 1];
            v.z = acc[i][j + 2]; v.w = acc[i][j + 3];
            if (bias) {
                v.x += bias[n]; v.y += bias[n + 1];
                v.z += bias[n + 2]; v.w += bias[n + 3];
            }
            *reinterpret_cast<float4*>(&C[(size_t)m * N + n]) = v;
        }
    }
}

// Fused QKV projection: grid.x in [0,24): 0..15 -> Q, 16..19 -> K, 20..23 -> V
__global__ __launch_bounds__(256) void qkv_gemm_kernel(
    const float* __restrict__ X,
    const float* __restrict__ qw, const float* __restrict__ qb,
    const float* __restrict__ kw, const float* __restrict__ kb,
    const float* __restrict__ vw, const float* __restrict__ vb,
    float* __restrict__ Qo, float* __restrict__ Ko, float* __restrict__ Vo)
{
    int bn = blockIdx.x;
    int m0 = blockIdx.y * 128;
    const float* W; const float* bias; float* C; int N; int n0;
    if (bn < 16)      { W = qw; bias = qb; C = Qo; N = NH  * HD; n0 = bn * 128; }
    else if (bn < 20) { W = kw; bias = kb; C = Ko; N = NKV * HD; n0 = (bn - 16) * 128; }
    else              { W = vw; bias = vb; C = Vo; N = NKV * HD; n0 = (bn - 20) * 128; }
    gemm_tile_body(X, W, bias, C, N, KDIM, m0, n0, threadIdx.x);
}

// Output projection: attn (4096 x 2048) @ o_w (2048 x 2048)
__global__ __launch_bounds__(256) void oproj_gemm_kernel(
    const float* __restrict__ A, const float* __restrict__ W,
    float* __restrict__ C)
{
    gemm_tile_body(A, W, nullptr, C, HID, NH * HD,
                   blockIdx.y * 128, blockIdx.x * 128, threadIdx.x);
}

// ---------------------------------------------------------------------------
// RoPE (interleaved pairs), in-place on Q and K workspace buffers.
// ---------------------------------------------------------------------------
__global__ __launch_bounds__(256) void rope_kernel(float* __restrict__ Q,
                                                   float* __restrict__ K)
{
    const int QP = BB * SS * NH  * (HD / 2);   // 4,194,304
    const int KP = BB * SS * NKV * (HD / 2);   // 1,048,576
    int idx = blockIdx.x * 256 + threadIdx.x;
    if (idx >= QP + KP) return;

    float* p;
    int s, j;
    if (idx < QP) {
        j = idx & 63;
        int t = idx >> 6;              // (b*S + s)*NH + h
        s = (t / NH) % SS;
        p = Q + (size_t)t * HD + 2 * j;
    } else {
        int i2 = idx - QP;
        j = i2 & 63;
        int t = i2 >> 6;               // (b*S + s)*NKV + h
        s = (t / NKV) % SS;
        p = K + (size_t)t * HD + 2 * j;
    }
    // freq = theta^(-j/64) ; ln(10000)/64 = 0.14391156831212787
    float freq = expf(-(float)j * 0.14391156831212787f);
    float ang = (float)s * freq;
    float sn, cs;
    sincosf(ang, &sn, &cs);
    float x1 = p[0], x2 = p[1];
    p[0] = x1 * cs - x2 * sn;
    p[1] = x1 * sn + x2 * cs;
}

// ---------------------------------------------------------------------------
// Causal GQA flash attention, fp32.
// Block: 256 threads. Grid: (S/64, NH, B). Q tile = 64 rows, K/V tile = 16.
// Score phase: thread (rq=tid&31, ck=tid>>5) computes rows {rq, rq+32} x
// keys {ck, ck+8}. Softmax/PV phase: thread (r=tid&63, dc=tid>>6) owns
// row r, d-range [dc*32, dc*32+32) with redundant per-row m/l tracking.
// ---------------------------------------------------------------------------
#define QB 64
#define KB 16

__global__ __launch_bounds__(256) void attn_kernel(
    const float* __restrict__ Q, const float* __restrict__ K,
    const float* __restrict__ V, float* __restrict__ O)
{
    __shared__ float Qs[QB][HD + 4];     // stride 132 (16B-aligned rows)
    __shared__ float Ks[KB][HD + 4];
    __shared__ float Vs[KB][HD + 4];
    __shared__ float Ss[QB][KB + 1];

    const int qt  = blockIdx.x;
    const int h   = blockIdx.y;
    const int b   = blockIdx.z;
    const int hkv = h >> 2;
    const int tid = threadIdx.x;
    const int q0  = qt * QB;
    const float scale = 0.08838834764831845f;  // 1/sqrt(128)

    // load Q tile: 64 x 128 floats
    {
        int col = (tid % 32) * 4;
        int rb  = tid / 32;               // 0..7
        #pragma unroll
        for (int p = 0; p < 8; ++p) {
            int r = p * 8 + rb;
            *reinterpret_cast<float4*>(&Qs[r][col]) =
                *reinterpret_cast<const float4*>(
                    &Q[((size_t)(b * SS + q0 + r) * NH + h) * HD + col]);
        }
    }

    const int r_own = tid & 63;
    const int dc    = tid >> 6;           // 0..3
    float m_run = -3.0e38f, l_run = 0.f;
    float o_acc[32];
    #pragma unroll
    for (int i = 0; i < 32; ++i) o_acc[i] = 0.f;

    const int rq = tid & 31;              // score rows rq, rq+32
    const int ck = tid >> 5;              // score keys ck, ck+8
    const int nk = (q0 + QB) / KB;        // exact

    for (int kt = 0; kt < nk; ++kt) {
        __syncthreads();   // previous PV done with Vs/Ss; Q visible on iter 0
        // load K,V tile: 16 x 128 each
        {
            int r = tid / 16;              // 0..15
            int c = (tid % 16) * 8;        // 0..120
            size_t base =
                ((size_t)(b * SS + kt * KB + r) * NKV + hkv) * HD + c;
            *reinterpret_cast<float4*>(&Ks[r][c]) =
                *reinterpret_cast<const float4*>(&K[base]);
            *reinterpret_cast<float4*>(&Ks[r][c + 4]) =
                *reinterpret_cast<const float4*>(&K[base + 4]);
            *reinterpret_cast<float4*>(&Vs[r][c]) =
                *reinterpret_cast<const float4*>(&V[base]);
            *reinterpret_cast<float4*>(&Vs[r][c + 4]) =
                *reinterpret_cast<const float4*>(&V[base + 4]);
        }
        __syncthreads();
        // scores: 2 rows x 2 keys per thread
        {
            float s00 = 0.f, s01 = 0.f, s10 = 0.f, s11 = 0.f;
            #pragma unroll 8
            for (int d = 0; d < HD; d += 4) {
                float4 qa = *reinterpret_cast<float4*>(&Qs[rq][d]);
                float4 qb = *reinterpret_cast<float4*>(&Qs[rq + 32][d]);
                float4 ka = *reinterpret_cast<float4*>(&Ks[ck][d]);
                float4 kb = *reinterpret_cast<float4*>(&Ks[ck + 8][d]);
                s00 += qa.x * ka.x + qa.y * ka.y + qa.z * ka.z + qa.w * ka.w;
                s01 += qa.x * kb.x + qa.y * kb.y + qa.z * kb.z + qa.w * kb.w;
                s10 += qb.x * ka.x + qb.y * ka.y + qb.z * ka.z + qb.w * ka.w;
                s11 += qb.x * kb.x + qb.y * kb.y + qb.z * kb.z + qb.w * kb.w;
            }
            int qg0 = q0 + rq, qg1 = q0 + rq + 32;
            int kg0 = kt * KB + ck, kg1 = kt * KB + ck + 8;
            Ss[rq][ck]          = (kg0 <= qg0) ? s00 * scale : -3.0e38f;
            Ss[rq][ck + 8]      = (kg1 <= qg0) ? s01 * scale : -3.0e38f;
            Ss[rq + 32][ck]     = (kg0 <= qg1) ? s10 * scale : -3.0e38f;
            Ss[rq + 32][ck + 8] = (kg1 <= qg1) ? s11 * scale : -3.0e38f;
        }
        __syncthreads();
        // softmax update + PV
        {
            float srow[KB];
            #pragma unroll
            for (int c = 0; c < KB; ++c) srow[c] = Ss[r_own][c];
            float tmax = srow[0];
            #pragma unroll
            for (int c = 1; c < KB; ++c) tmax = fmaxf(tmax, srow[c]);
            float m_new = fmaxf(m_run, tmax);
            float corr = expf(m_run - m_new);   // 0 when m_run = -3e38
            l_run *= corr;
            #pragma unroll
            for (int i = 0; i < 32; ++i) o_acc[i] *= corr;
            #pragma unroll
            for (int c = 0; c < KB; ++c) {
                float e = expf(srow[c] - m_new);
                l_run += e;
                const float* vrow = &Vs[c][dc * 32];
                #pragma unroll
                for (int i = 0; i < 32; i += 4) {
                    float4 vv = *reinterpret_cast<const float4*>(&vrow[i]);
                    o_acc[i]     = fmaf(e, vv.x, o_acc[i]);
                    o_acc[i + 1] = fmaf(e, vv.y, o_acc[i + 1]);
                    o_acc[i + 2] = fmaf(e, vv.z, o_acc[i + 2]);
                    o_acc[i + 3] = fmaf(e, vv.w, o_acc[i + 3]);
                }
            }
            m_run = m_new;
        }
    }
    // write normalized output
    float inv_l = 1.0f / l_run;
    float* dst = O + ((size_t)(b * SS + q0 + r_own) * NH + h) * HD + dc * 32;
    #pragma unroll
    for (int i = 0; i < 32; i += 4) {
        float4 v;
        v.x = o_acc[i] * inv_l;     v.y = o_acc[i + 1] * inv_l;
        v.z = o_acc[i + 2] * inv_l; v.w = o_acc[i + 3] * inv_l;
        *reinterpret_cast<float4*>(&dst[i]) = v;
    }
}

// ---------------------------------------------------------------------------
extern "C" void kernel_launch(void* const* d_in, const int* in_sizes, int n_in,
                              void* d_out, int out_size, void* d_ws, size_t ws_size,
                              hipStream_t stream)
{
    const float* hidden = (const float*)d_in[0];
    const float* q_w    = (const float*)d_in[1];
    const float* q_b    = (const float*)d_in[2];
    const float* k_w    = (const float*)d_in[3];
    const float* k_b    = (const float*)d_in[4];
    const float* v_w    = (const float*)d_in[5];
    const float* v_b    = (const float*)d_in[6];
    const float* o_w    = (const float*)d_in[7];
    float* out = (float*)d_out;

    // workspace layout (floats): Q | K | V | A   (80 MB total)
    float* Qb = (float*)d_ws;
    float* Kb = Qb + (size_t)MTOT * NH  * HD;
    float* Vb = Kb + (size_t)MTOT * NKV * HD;
    float* Ab = Vb + (size_t)MTOT * NKV * HD;

    // 1) fused QKV projections
    qkv_gemm_kernel<<<dim3(24, MTOT / 128), 256, 0, stream>>>(
        hidden, q_w, q_b, k_w, k_b, v_w, v_b, Qb, Kb, Vb);

    // 2) RoPE on Q and K
    {
        int total = BB * SS * (NH + NKV) * (HD / 2);
        rope_kernel<<<(total + 255) / 256, 256, 0, stream>>>(Qb, Kb);
    }

    // 3) causal GQA flash attention
    attn_kernel<<<dim3(SS / QB, NH, BB), 256, 0, stream>>>(Qb, Kb, Vb, Ab);

    // 4) output projection
    oproj_gemm_kernel<<<dim3(HID / 128, MTOT / 128), 256, 0, stream>>>(
        Ab, o_w, out);
}

// Round 2
// 703.687 us; speedup vs baseline: 4.1231x; 4.1231x over previous
//
#include <hip/hip_runtime.h>
#include <hip/hip_bf16.h>
#include <math.h>

#define BB 2
#define SS 2048
#define HID 2048
#define NH 16
#define NKV 4
#define HD 128

typedef __bf16 bf16_t;
typedef bf16_t bf16x8 __attribute__((ext_vector_type(8)));
typedef float f32x4 __attribute__((ext_vector_type(4)));

#define AS1 __attribute__((address_space(1)))
#define AS3 __attribute__((address_space(3)))

__device__ __forceinline__ void gload16(const bf16_t* g, bf16_t* lds) {
    __builtin_amdgcn_global_load_lds((const AS1 void*)g, (AS3 void*)lds, 16, 0, 0);
}

// ---------------------------------------------------------------------------
// Prep kernels
// ---------------------------------------------------------------------------
__global__ __launch_bounds__(256) void rope_tab_kernel(float2* __restrict__ tab)
{
    int i = blockIdx.x * 256 + threadIdx.x;       // s*64 + j, 131072 total
    int j = i & 63, s = i >> 6;
    float freq = expf(-(float)j * 0.14391156831212787f);  // ln(10000)/64
    float sn, cs;
    sincosf((float)s * freq, &sn, &cs);
    tab[i] = make_float2(cs, sn);
}

__global__ __launch_bounds__(256) void cast_hidden_kernel(
    const float* __restrict__ X, bf16_t* __restrict__ Xb)
{
    size_t i = (size_t)(blockIdx.x * 256 + threadIdx.x) * 8;
    float4 a = *reinterpret_cast<const float4*>(X + i);
    float4 b = *reinterpret_cast<const float4*>(X + i + 4);
    bf16x8 v = { (bf16_t)a.x, (bf16_t)a.y, (bf16_t)a.z, (bf16_t)a.w,
                 (bf16_t)b.x, (bf16_t)b.y, (bf16_t)b.z, (bf16_t)b.w };
    *reinterpret_cast<bf16x8*>(Xb + i) = v;
}

// W [K=2048][N] fp32 -> Wt [N][2048] bf16, tiled 32x32 via LDS
__global__ __launch_bounds__(256) void transpose_cast_kernel(
    const float* __restrict__ q_w, const float* __restrict__ k_w,
    const float* __restrict__ v_w, const float* __restrict__ o_w,
    bf16_t* __restrict__ Wq, bf16_t* __restrict__ Wk,
    bf16_t* __restrict__ Wv, bf16_t* __restrict__ Wo)
{
    __shared__ float tile[32][33];
    const float* W; bf16_t* Wt; int N;
    switch (blockIdx.z) {
        case 0: W = q_w; Wt = Wq; N = 2048; break;
        case 1: W = k_w; Wt = Wk; N = 512;  break;
        case 2: W = v_w; Wt = Wv; N = 512;  break;
        default: W = o_w; Wt = Wo; N = 2048; break;
    }
    int n0 = blockIdx.x * 32, k0 = blockIdx.y * 32;
    if (n0 >= N) return;
    int c = threadIdx.x & 31, r0 = threadIdx.x >> 5;   // 8 rows/pass
    #pragma unroll
    for (int rr = 0; rr < 32; rr += 8)
        tile[r0 + rr][c] = W[(size_t)(k0 + r0 + rr) * N + n0 + c];
    __syncthreads();
    #pragma unroll
    for (int rr = 0; rr < 32; rr += 8)
        Wt[(size_t)(n0 + r0 + rr) * HID + k0 + c] = (bf16_t)tile[c][r0 + rr];
}

// ---------------------------------------------------------------------------
// bf16 MFMA GEMM core: 128x128 tile, BK=32, 4 waves (2x2), 16x16x32 MFMA.
// A [M][2048] row-major bf16; Bt [N][2048] row-major bf16 (i.e. B transposed).
// global_load_lds width-16 staging into linear LDS [128][32].
// ---------------------------------------------------------------------------
__device__ __forceinline__ void gemm_core_bf16(
    const bf16_t* __restrict__ A, const bf16_t* __restrict__ Bt,
    int m0, int n0, bf16_t* As, bf16_t* Bs, f32x4 acc[4][4])
{
    const int t = threadIdx.x;
    const int w = t >> 6, lane = t & 63, lo = lane & 15, hi = lane >> 4;
    const int wr = (w >> 1) * 64, wc = (w & 1) * 64;

    for (int k0 = 0; k0 < HID; k0 += 32) {
        __syncthreads();
        #pragma unroll
        for (int i = 0; i < 2; ++i) {
            int j = t + i * 256;                    // 16B chunk index 0..511
            gload16(A  + (size_t)(m0 + (j >> 2)) * HID + k0 + (j & 3) * 8,
                    As + (size_t)(w * 64 + i * 256) * 8);
            gload16(Bt + (size_t)(n0 + (j >> 2)) * HID + k0 + (j & 3) * 8,
                    Bs + (size_t)(w * 64 + i * 256) * 8);
        }
        __syncthreads();
        const bf16x8* Av = reinterpret_cast<const bf16x8*>(As);
        const bf16x8* Bv = reinterpret_cast<const bf16x8*>(Bs);
        bf16x8 a[4], b[4];
        #pragma unroll
        for (int m = 0; m < 4; ++m) a[m] = Av[(wr + m * 16 + lo) * 4 + hi];
        #pragma unroll
        for (int n = 0; n < 4; ++n) b[n] = Bv[(wc + n * 16 + lo) * 4 + hi];
        #pragma unroll
        for (int m = 0; m < 4; ++m)
            #pragma unroll
            for (int n = 0; n < 4; ++n)
                acc[m][n] = __builtin_amdgcn_mfma_f32_16x16x32_bf16(
                    a[m], b[n], acc[m][n], 0, 0, 0);
    }
}

// ---------------------------------------------------------------------------
// Fused QKV projection + bias + RoPE + layout shuffle.
// grid.x: 0..15 Q-heads, 16..19 K-heads, 20..23 V-heads. grid.y: m-tiles.
// Q -> [b][h][s][d] bf16 ; K -> [b][hkv][s][d] bf16 ; V -> [b][hkv][d][s] bf16
// ---------------------------------------------------------------------------
__global__ __launch_bounds__(256) void qkv_gemm_kernel(
    const bf16_t* __restrict__ X,
    const bf16_t* __restrict__ Wq, const bf16_t* __restrict__ Wk,
    const bf16_t* __restrict__ Wv,
    const float* __restrict__ qb, const float* __restrict__ kb,
    const float* __restrict__ vb,
    const float2* __restrict__ rope_tab,
    bf16_t* __restrict__ Qo, bf16_t* __restrict__ Ko, bf16_t* __restrict__ Vt)
{
    __shared__ bf16_t As[128 * 32], Bs[128 * 32];
    f32x4 acc[4][4];
    #pragma unroll
    for (int m = 0; m < 4; ++m)
        #pragma unroll
        for (int n = 0; n < 4; ++n) acc[m][n] = (f32x4){0.f, 0.f, 0.f, 0.f};

    const int bn = blockIdx.x, m0 = blockIdx.y * 128;
    const bf16_t* Bt; const float* bias; int mode, head;
    if (bn < 16)      { Bt = Wq; bias = qb; mode = 0; head = bn; }
    else if (bn < 20) { Bt = Wk; bias = kb; mode = 1; head = bn - 16; }
    else              { Bt = Wv; bias = vb; mode = 2; head = bn - 20; }

    gemm_core_bf16(X, Bt, m0, head * 128, As, Bs, acc);

    const int t = threadIdx.x, w = t >> 6, lane = t & 63;
    const int lo = lane & 15, hi = lane >> 4;
    const int wr = (w >> 1) * 64, wc = (w & 1) * 64;

    #pragma unroll
    for (int n = 0; n < 4; ++n) {
        const int d = wc + n * 16 + lo;              // 0..127 within head
        const float bv = bias[head * 128 + d];
        const int jj = d >> 1;
        #pragma unroll
        for (int m = 0; m < 4; ++m) {
            #pragma unroll
            for (int r = 0; r < 4; ++r) {
                const int row = m0 + wr + m * 16 + hi * 4 + r;   // b*S + s
                const int b = row >> 11, s = row & 2047;
                float v = acc[m][n][r] + bv;
                if (mode < 2) {
                    float2 cs = rope_tab[s * 64 + jj];
                    float p = __shfl_xor(v, 1);
                    v = (d & 1) ? (p * cs.y + v * cs.x)
                                : (v * cs.x - p * cs.y);
                    if (mode == 0)
                        Qo[((size_t)(b * NH + head) * SS + s) * HD + d] = (bf16_t)v;
                    else
                        Ko[((size_t)(b * NKV + head) * SS + s) * HD + d] = (bf16_t)v;
                } else {
                    Vt[((size_t)(b * NKV + head) * HD + d) * SS + s] = (bf16_t)v;
                }
            }
        }
    }
}

// ---------------------------------------------------------------------------
// Output projection: Ab [4096][2048] bf16 @ o_w -> out fp32 [4096][2048]
// ---------------------------------------------------------------------------
__global__ __launch_bounds__(256) void oproj_gemm_kernel(
    const bf16_t* __restrict__ Ab, const bf16_t* __restrict__ Wo,
    float* __restrict__ out)
{
    __shared__ bf16_t As[128 * 32], Bs[128 * 32];
    f32x4 acc[4][4];
    #pragma unroll
    for (int m = 0; m < 4; ++m)
        #pragma unroll
        for (int n = 0; n < 4; ++n) acc[m][n] = (f32x4){0.f, 0.f, 0.f, 0.f};

    const int m0 = blockIdx.y * 128, n0 = blockIdx.x * 128;
    gemm_core_bf16(Ab, Wo, m0, n0, As, Bs, acc);

    const int t = threadIdx.x, w = t >> 6, lane = t & 63;
    const int lo = lane & 15, hi = lane >> 4;
    const int wr = (w >> 1) * 64, wc = (w & 1) * 64;
    #pragma unroll
    for (int m = 0; m < 4; ++m)
        #pragma unroll
        for (int n = 0; n < 4; ++n)
            #pragma unroll
            for (int r = 0; r < 4; ++r) {
                int row = m0 + wr + m * 16 + hi * 4 + r;
                int col = n0 + wc + n * 16 + lo;
                out[(size_t)row * HID + col] = acc[m][n][r];
            }
}

// ---------------------------------------------------------------------------
// MFMA flash attention. 1 wave = 16 q-rows; block = 4 waves (no barriers).
// Q [b][h][s][d], K [b][hkv][s][d], Vt [b][hkv][d][s]; out Ab [b*s][h*128].
// KB=32 keys/iter: QK^T = 8 MFMA, PV = 8 MFMA; online softmax in registers.
// ---------------------------------------------------------------------------
__global__ __launch_bounds__(256) void attn_kernel(
    const bf16_t* __restrict__ Q, const bf16_t* __restrict__ K,
    const bf16_t* __restrict__ Vt, bf16_t* __restrict__ O)
{
    __shared__ bf16_t Ps[4][16 * 32];         // per-wave P buffer (1 KB each)
    const int t = threadIdx.x, w = t >> 6, lane = t & 63;
    const int lo = lane & 15, hi = lane >> 4;
    const int h = blockIdx.y, b = blockIdx.z, hkv = h >> 2;
    const int q0 = (blockIdx.x * 4 + w) * 16;
    const float scale = 0.08838834764831845f;   // 1/sqrt(128)

    const bf16_t* Qh = Q  + (size_t)(b * NH  + h)   * SS * HD;
    const bf16_t* Kh = K  + (size_t)(b * NKV + hkv) * SS * HD;
    const bf16_t* Vh = Vt + (size_t)(b * NKV + hkv) * HD * SS;

    bf16x8 qf[4];
    #pragma unroll
    for (int c = 0; c < 4; ++c)
        qf[c] = *reinterpret_cast<const bf16x8*>(
            Qh + (size_t)(q0 + lo) * HD + c * 32 + hi * 8);

    f32x4 of[8];
    #pragma unroll
    for (int n = 0; n < 8; ++n) of[n] = (f32x4){0.f, 0.f, 0.f, 0.f};
    float m_run[4], l_run[4];
    #pragma unroll
    for (int r = 0; r < 4; ++r) { m_run[r] = -3.0e38f; l_run[r] = 0.f; }

    bf16_t* ps = Ps[w];
    const int nk = (q0 >> 5) + 1;

    for (int kt = 0; kt < nk; ++kt) {
        const int k0 = kt * 32;
        f32x4 sfr[2];
        sfr[0] = (f32x4){0.f, 0.f, 0.f, 0.f};
        sfr[1] = (f32x4){0.f, 0.f, 0.f, 0.f};
        #pragma unroll
        for (int kg = 0; kg < 2; ++kg) {
            const bf16_t* kp = Kh + (size_t)(k0 + kg * 16 + lo) * HD + hi * 8;
            #pragma unroll
            for (int c = 0; c < 4; ++c) {
                bf16x8 kf = *reinterpret_cast<const bf16x8*>(kp + c * 32);
                sfr[kg] = __builtin_amdgcn_mfma_f32_16x16x32_bf16(
                    qf[c], kf, sfr[kg], 0, 0, 0);
            }
        }
        // scale + causal mask + per-row tile max
        float mrow[4];
        #pragma unroll
        for (int r = 0; r < 4; ++r) {
            const int qg = q0 + hi * 4 + r;
            float s0 = sfr[0][r] * scale;
            float s1 = sfr[1][r] * scale;
            if (k0 + lo > qg)      s0 = -3.0e38f;
            if (k0 + 16 + lo > qg) s1 = -3.0e38f;
            sfr[0][r] = s0; sfr[1][r] = s1;
            mrow[r] = fmaxf(s0, s1);
        }
        #pragma unroll
        for (int mask = 1; mask < 16; mask <<= 1)
            #pragma unroll
            for (int r = 0; r < 4; ++r)
                mrow[r] = fmaxf(mrow[r], __shfl_xor(mrow[r], mask));
        // online softmax update
        float corr[4], psum[4];
        #pragma unroll
        for (int r = 0; r < 4; ++r) {
            float mnew = fmaxf(m_run[r], mrow[r]);
            corr[r] = expf(m_run[r] - mnew);
            m_run[r] = mnew;
            float e0 = expf(sfr[0][r] - mnew);
            float e1 = expf(sfr[1][r] - mnew);
            sfr[0][r] = e0; sfr[1][r] = e1;
            psum[r] = e0 + e1;
        }
        #pragma unroll
        for (int mask = 1; mask < 16; mask <<= 1)
            #pragma unroll
            for (int r = 0; r < 4; ++r)
                psum[r] += __shfl_xor(psum[r], mask);
        #pragma unroll
        for (int r = 0; r < 4; ++r)
            l_run[r] = l_run[r] * corr[r] + psum[r];
        #pragma unroll
        for (int n = 0; n < 8; ++n)
            #pragma unroll
            for (int r = 0; r < 4; ++r)
                of[n][r] *= corr[r];
        // P -> LDS (C-layout) -> A-fragment
        #pragma unroll
        for (int r = 0; r < 4; ++r) {
            ps[(hi * 4 + r) * 32 + lo]      = (bf16_t)sfr[0][r];
            ps[(hi * 4 + r) * 32 + 16 + lo] = (bf16_t)sfr[1][r];
        }
        bf16x8 pf = *reinterpret_cast<const bf16x8*>(ps + lo * 32 + hi * 8);
        // PV
        #pragma unroll
        for (int n = 0; n < 8; ++n) {
            bf16x8 vf = *reinterpret_cast<const bf16x8*>(
                Vh + (size_t)(n * 16 + lo) * SS + k0 + hi * 8);
            of[n] = __builtin_amdgcn_mfma_f32_16x16x32_bf16(
                pf, vf, of[n], 0, 0, 0);
        }
    }
    // epilogue: normalize, write [b*s][h*128+d] bf16
    float inv_l[4];
    #pragma unroll
    for (int r = 0; r < 4; ++r) inv_l[r] = 1.0f / l_run[r];
    #pragma unroll
    for (int n = 0; n < 8; ++n)
        #pragma unroll
        for (int r = 0; r < 4; ++r) {
            const int q = q0 + hi * 4 + r;
            O[((size_t)(b * SS + q)) * HID + h * HD + n * 16 + lo] =
                (bf16_t)(of[n][r] * inv_l[r]);
        }
}

// ---------------------------------------------------------------------------
extern "C" void kernel_launch(void* const* d_in, const int* in_sizes, int n_in,
                              void* d_out, int out_size, void* d_ws, size_t ws_size,
                              hipStream_t stream)
{
    const float* hidden = (const float*)d_in[0];
    const float* q_w    = (const float*)d_in[1];
    const float* q_b    = (const float*)d_in[2];
    const float* k_w    = (const float*)d_in[3];
    const float* k_b    = (const float*)d_in[4];
    const float* v_w    = (const float*)d_in[5];
    const float* v_b    = (const float*)d_in[6];
    const float* o_w    = (const float*)d_in[7];
    float* out = (float*)d_out;

    // workspace layout (bf16 elements unless noted); total ~77 MiB
    bf16_t* p  = (bf16_t*)d_ws;
    bf16_t* Xb = p; p += (size_t)4096 * 2048;
    bf16_t* Wq = p; p += (size_t)2048 * 2048;
    bf16_t* Wk = p; p += (size_t)512  * 2048;
    bf16_t* Wv = p; p += (size_t)512  * 2048;
    bf16_t* Wo = p; p += (size_t)2048 * 2048;
    bf16_t* Qb = p; p += (size_t)BB * NH  * SS * HD;
    bf16_t* Kb = p; p += (size_t)BB * NKV * SS * HD;
    bf16_t* Vt = p; p += (size_t)BB * NKV * HD * SS;
    bf16_t* Ab = p; p += (size_t)4096 * 2048;
    float2* rope_tab = (float2*)p;               // 2048*64 float2 = 1 MiB

    rope_tab_kernel<<<512, 256, 0, stream>>>(rope_tab);
    cast_hidden_kernel<<<4096, 256, 0, stream>>>(hidden, Xb);
    transpose_cast_kernel<<<dim3(64, 64, 4), 256, 0, stream>>>(
        q_w, k_w, v_w, o_w, Wq, Wk, Wv, Wo);
    qkv_gemm_kernel<<<dim3(24, 32), 256, 0, stream>>>(
        Xb, Wq, Wk, Wv, q_b, k_b, v_b, rope_tab, Qb, Kb, Vt);
    attn_kernel<<<dim3(32, 16, 2), 256, 0, stream>>>(Qb, Kb, Vt, Ab);
    oproj_gemm_kernel<<<dim3(16, 32), 256, 0, stream>>>(Ab, Wo, out);
}

// Round 3
// 457.700 us; speedup vs baseline: 6.3390x; 1.5374x over previous
//
#include <hip/hip_runtime.h>
#include <hip/hip_bf16.h>
#include <math.h>

#define BB 2
#define SS 2048
#define HID 2048
#define NH 16
#define NKV 4
#define HD 128

typedef __bf16 bf16_t;
typedef bf16_t bf16x8 __attribute__((ext_vector_type(8)));
typedef bf16_t bf16x4 __attribute__((ext_vector_type(4)));
typedef float f32x4 __attribute__((ext_vector_type(4)));

#define AS1 __attribute__((address_space(1)))
#define AS3 __attribute__((address_space(3)))

__device__ __forceinline__ void gload16(const bf16_t* g, bf16_t* lds) {
    __builtin_amdgcn_global_load_lds((const AS1 void*)g, (AS3 void*)lds, 16, 0, 0);
}

// ---------------------------------------------------------------------------
// Prep kernels
// ---------------------------------------------------------------------------
__global__ __launch_bounds__(256) void rope_tab_kernel(float2* __restrict__ tab)
{
    int i = blockIdx.x * 256 + threadIdx.x;       // s*64 + j, 131072 total
    int j = i & 63, s = i >> 6;
    float freq = expf(-(float)j * 0.14391156831212787f);  // ln(10000)/64
    float sn, cs;
    sincosf((float)s * freq, &sn, &cs);
    tab[i] = make_float2(cs, sn);
}

__global__ __launch_bounds__(256) void cast_hidden_kernel(
    const float* __restrict__ X, bf16_t* __restrict__ Xb)
{
    size_t i = (size_t)(blockIdx.x * 256 + threadIdx.x) * 8;
    float4 a = *reinterpret_cast<const float4*>(X + i);
    float4 b = *reinterpret_cast<const float4*>(X + i + 4);
    bf16x8 v = { (bf16_t)a.x, (bf16_t)a.y, (bf16_t)a.z, (bf16_t)a.w,
                 (bf16_t)b.x, (bf16_t)b.y, (bf16_t)b.z, (bf16_t)b.w };
    *reinterpret_cast<bf16x8*>(Xb + i) = v;
}

// W [K=2048][N] fp32 -> Wt [N][2048] bf16, tiled 32x32 via LDS
__global__ __launch_bounds__(256) void transpose_cast_kernel(
    const float* __restrict__ q_w, const float* __restrict__ k_w,
    const float* __restrict__ v_w, const float* __restrict__ o_w,
    bf16_t* __restrict__ Wq, bf16_t* __restrict__ Wk,
    bf16_t* __restrict__ Wv, bf16_t* __restrict__ Wo)
{
    __shared__ float tile[32][33];
    const float* W; bf16_t* Wt; int N;
    switch (blockIdx.z) {
        case 0: W = q_w; Wt = Wq; N = 2048; break;
        case 1: W = k_w; Wt = Wk; N = 512;  break;
        case 2: W = v_w; Wt = Wv; N = 512;  break;
        default: W = o_w; Wt = Wo; N = 2048; break;
    }
    int n0 = blockIdx.x * 32, k0 = blockIdx.y * 32;
    if (n0 >= N) return;
    int c = threadIdx.x & 31, r0 = threadIdx.x >> 5;   // 8 rows/pass
    #pragma unroll
    for (int rr = 0; rr < 32; rr += 8)
        tile[r0 + rr][c] = W[(size_t)(k0 + r0 + rr) * N + n0 + c];
    __syncthreads();
    #pragma unroll
    for (int rr = 0; rr < 32; rr += 8)
        Wt[(size_t)(n0 + r0 + rr) * HID + k0 + c] = (bf16_t)tile[c][r0 + rr];
}

// ---------------------------------------------------------------------------
// bf16 MFMA GEMM core: 128x128 tile, BK=32, 4 waves (2x2), 16x16x32 MFMA.
// ---------------------------------------------------------------------------
__device__ __forceinline__ void gemm_core_bf16(
    const bf16_t* __restrict__ A, const bf16_t* __restrict__ Bt,
    int m0, int n0, bf16_t* As, bf16_t* Bs, f32x4 acc[4][4])
{
    const int t = threadIdx.x;
    const int w = t >> 6, lane = t & 63, lo = lane & 15, hi = lane >> 4;
    const int wr = (w >> 1) * 64, wc = (w & 1) * 64;

    for (int k0 = 0; k0 < HID; k0 += 32) {
        __syncthreads();
        #pragma unroll
        for (int i = 0; i < 2; ++i) {
            int j = t + i * 256;                    // 16B chunk index 0..511
            gload16(A  + (size_t)(m0 + (j >> 2)) * HID + k0 + (j & 3) * 8,
                    As + (size_t)(w * 64 + i * 256) * 8);
            gload16(Bt + (size_t)(n0 + (j >> 2)) * HID + k0 + (j & 3) * 8,
                    Bs + (size_t)(w * 64 + i * 256) * 8);
        }
        __syncthreads();
        const bf16x8* Av = reinterpret_cast<const bf16x8*>(As);
        const bf16x8* Bv = reinterpret_cast<const bf16x8*>(Bs);
        bf16x8 a[4], b[4];
        #pragma unroll
        for (int m = 0; m < 4; ++m) a[m] = Av[(wr + m * 16 + lo) * 4 + hi];
        #pragma unroll
        for (int n = 0; n < 4; ++n) b[n] = Bv[(wc + n * 16 + lo) * 4 + hi];
        #pragma unroll
        for (int m = 0; m < 4; ++m)
            #pragma unroll
            for (int n = 0; n < 4; ++n)
                acc[m][n] = __builtin_amdgcn_mfma_f32_16x16x32_bf16(
                    a[m], b[n], acc[m][n], 0, 0, 0);
    }
}

// ---------------------------------------------------------------------------
// Fused QKV projection + bias + RoPE + layout shuffle.
// ---------------------------------------------------------------------------
__global__ __launch_bounds__(256) void qkv_gemm_kernel(
    const bf16_t* __restrict__ X,
    const bf16_t* __restrict__ Wq, const bf16_t* __restrict__ Wk,
    const bf16_t* __restrict__ Wv,
    const float* __restrict__ qb, const float* __restrict__ kb,
    const float* __restrict__ vb,
    const float2* __restrict__ rope_tab,
    bf16_t* __restrict__ Qo, bf16_t* __restrict__ Ko, bf16_t* __restrict__ Vt)
{
    __shared__ bf16_t As[128 * 32], Bs[128 * 32];
    f32x4 acc[4][4];
    #pragma unroll
    for (int m = 0; m < 4; ++m)
        #pragma unroll
        for (int n = 0; n < 4; ++n) acc[m][n] = (f32x4){0.f, 0.f, 0.f, 0.f};

    const int bn = blockIdx.x, m0 = blockIdx.y * 128;
    const bf16_t* Bt; const float* bias; int mode, head;
    if (bn < 16)      { Bt = Wq; bias = qb; mode = 0; head = bn; }
    else if (bn < 20) { Bt = Wk; bias = kb; mode = 1; head = bn - 16; }
    else              { Bt = Wv; bias = vb; mode = 2; head = bn - 20; }

    gemm_core_bf16(X, Bt, m0, head * 128, As, Bs, acc);

    const int t = threadIdx.x, w = t >> 6, lane = t & 63;
    const int lo = lane & 15, hi = lane >> 4;
    const int wr = (w >> 1) * 64, wc = (w & 1) * 64;

    #pragma unroll
    for (int n = 0; n < 4; ++n) {
        const int d = wc + n * 16 + lo;              // 0..127 within head
        const float bv = bias[head * 128 + d];
        const int jj = d >> 1;
        #pragma unroll
        for (int m = 0; m < 4; ++m) {
            #pragma unroll
            for (int r = 0; r < 4; ++r) {
                const int row = m0 + wr + m * 16 + hi * 4 + r;   // b*S + s
                const int b = row >> 11, s = row & 2047;
                float v = acc[m][n][r] + bv;
                if (mode < 2) {
                    float2 cs = rope_tab[s * 64 + jj];
                    float p = __shfl_xor(v, 1);
                    v = (d & 1) ? (p * cs.y + v * cs.x)
                                : (v * cs.x - p * cs.y);
                    if (mode == 0)
                        Qo[((size_t)(b * NH + head) * SS + s) * HD + d] = (bf16_t)v;
                    else
                        Ko[((size_t)(b * NKV + head) * SS + s) * HD + d] = (bf16_t)v;
                } else {
                    Vt[((size_t)(b * NKV + head) * HD + d) * SS + s] = (bf16_t)v;
                }
            }
        }
    }
}

// ---------------------------------------------------------------------------
// Output projection
// ---------------------------------------------------------------------------
__global__ __launch_bounds__(256) void oproj_gemm_kernel(
    const bf16_t* __restrict__ Ab, const bf16_t* __restrict__ Wo,
    float* __restrict__ out)
{
    __shared__ bf16_t As[128 * 32], Bs[128 * 32];
    f32x4 acc[4][4];
    #pragma unroll
    for (int m = 0; m < 4; ++m)
        #pragma unroll
        for (int n = 0; n < 4; ++n) acc[m][n] = (f32x4){0.f, 0.f, 0.f, 0.f};

    const int m0 = blockIdx.y * 128, n0 = blockIdx.x * 128;
    gemm_core_bf16(Ab, Wo, m0, n0, As, Bs, acc);

    const int t = threadIdx.x, w = t >> 6, lane = t & 63;
    const int lo = lane & 15, hi = lane >> 4;
    const int wr = (w >> 1) * 64, wc = (w & 1) * 64;
    #pragma unroll
    for (int m = 0; m < 4; ++m)
        #pragma unroll
        for (int n = 0; n < 4; ++n)
            #pragma unroll
            for (int r = 0; r < 4; ++r) {
                int row = m0 + wr + m * 16 + hi * 4 + r;
                int col = n0 + wc + n * 16 + lo;
                out[(size_t)row * HID + col] = acc[m][n][r];
            }
}

// ---------------------------------------------------------------------------
// MFMA flash attention v2: swapped QK^T + defer-max + paired q-tiles.
// Wave owns 16 rows of supertile qp AND 16 rows of supertile 31-qp.
// KB=32. Scores S^T[key][q]: q = lane&15 (lane-local softmax rows).
// P staged per-wave in LDS in A-frag gather order (read = lane*16B linear).
// ---------------------------------------------------------------------------
__device__ __forceinline__ void softmax_group(
    f32x4* sfr, float& m_run, float& l_run, f32x4* of,
    bf16_t* pbuf, int qrow, int k0, int lo, int hi)
{
    const float cscale = 0.12746231410988061f;  // (1/sqrt(128)) * log2(e)
    float s[8];
    #pragma unroll
    for (int kg = 0; kg < 2; ++kg)
        #pragma unroll
        for (int r = 0; r < 4; ++r) {
            int key = k0 + kg * 16 + hi * 4 + r;
            float v = sfr[kg][r] * cscale;
            s[kg * 4 + r] = (key <= qrow) ? v : -3.0e38f;
        }
    float pmax = s[0];
    #pragma unroll
    for (int i = 1; i < 8; ++i) pmax = fmaxf(pmax, s[i]);
    pmax = fmaxf(pmax, __shfl_xor(pmax, 16));
    pmax = fmaxf(pmax, __shfl_xor(pmax, 32));
    if (!__all(pmax - m_run <= 11.5f)) {        // defer-max (T13)
        float mnew = fmaxf(m_run, pmax);
        float corr = exp2f(m_run - mnew);
        m_run = mnew;
        l_run *= corr;
        #pragma unroll
        for (int r = 0; r < 4; ++r) {
            float cr = __shfl(corr, hi * 4 + r);
            #pragma unroll
            for (int n = 0; n < 8; ++n) of[n][r] *= cr;
        }
    }
    float e[8];
    float ps = 0.f;
    #pragma unroll
    for (int i = 0; i < 8; ++i) { e[i] = exp2f(s[i] - m_run); ps += e[i]; }
    ps += __shfl_xor(ps, 16);
    ps += __shfl_xor(ps, 32);
    l_run += ps;
    // write P in A-frag gather order: chunk for read-lane (oct*16+q) at lane*16B
    #pragma unroll
    for (int kg = 0; kg < 2; ++kg) {
        bf16x4 pk;
        #pragma unroll
        for (int r = 0; r < 4; ++r) pk[r] = (bf16_t)e[kg * 4 + r];
        int oct = kg * 2 + (hi >> 1);
        *reinterpret_cast<bf16x4*>(pbuf + (oct * 16 + lo) * 8 + (hi & 1) * 4) = pk;
    }
}

__global__ __launch_bounds__(256, 2) void attn_kernel(
    const bf16_t* __restrict__ Q, const bf16_t* __restrict__ K,
    const bf16_t* __restrict__ Vt, bf16_t* __restrict__ O)
{
    __shared__ bf16_t Ps[4][2][512];          // [wave][group][64 lanes * 8]
    const int t = threadIdx.x, w = t >> 6, lane = t & 63;
    const int lo = lane & 15, hi = lane >> 4;
    const int id = blockIdx.x;                // 512 blocks
    const int b = (id >> 2) & 1, hkv = id & 3;   // id&7 -> XCD-local (b,hkv)
    const int rest = id >> 3;
    const int h = hkv * 4 + (rest & 3);
    const int qp = rest >> 2;                 // 0..15 pair index
    const int qA0 = qp * 64 + w * 16;
    const int qB0 = (31 - qp) * 64 + w * 16;

    const bf16_t* Qh = Q  + (size_t)(b * NH  + h)   * SS * HD;
    const bf16_t* Kh = K  + (size_t)(b * NKV + hkv) * SS * HD;
    const bf16_t* Vh = Vt + (size_t)(b * NKV + hkv) * HD * SS;

    bf16x8 qfA[4], qfB[4];
    #pragma unroll
    for (int c = 0; c < 4; ++c) {
        qfA[c] = *reinterpret_cast<const bf16x8*>(
            Qh + (size_t)(qA0 + lo) * HD + c * 32 + hi * 8);
        qfB[c] = *reinterpret_cast<const bf16x8*>(
            Qh + (size_t)(qB0 + lo) * HD + c * 32 + hi * 8);
    }

    f32x4 ofA[8], ofB[8];
    #pragma unroll
    for (int n = 0; n < 8; ++n) {
        ofA[n] = (f32x4){0.f, 0.f, 0.f, 0.f};
        ofB[n] = (f32x4){0.f, 0.f, 0.f, 0.f};
    }
    float mA = -3.0e38f, lAcc = 0.f, mB = -3.0e38f, lBcc = 0.f;

    const int aLast = (qA0 + 15) >> 5;
    const int nk    = ((qB0 + 15) >> 5) + 1;

    // prefetch K tile 0
    bf16x8 kf[2][4];
    #pragma unroll
    for (int kg = 0; kg < 2; ++kg)
        #pragma unroll
        for (int c = 0; c < 4; ++c)
            kf[kg][c] = *reinterpret_cast<const bf16x8*>(
                Kh + (size_t)(kg * 16 + lo) * HD + c * 32 + hi * 8);

    bf16_t* pbufA = &Ps[w][0][0];
    bf16_t* pbufB = &Ps[w][1][0];

    for (int kt = 0; kt < nk; ++kt) {
        const int k0 = kt << 5;
        const bool aAct = (kt <= aLast);
        // V loads for this tile (consumed at the bottom)
        bf16x8 vf[8];
        #pragma unroll
        for (int n = 0; n < 8; ++n)
            vf[n] = *reinterpret_cast<const bf16x8*>(
                Vh + (size_t)(n * 16 + lo) * SS + k0 + hi * 8);
        // QK^T (swapped): C[key][q]
        f32x4 sfrA[2], sfrB[2];
        #pragma unroll
        for (int kg = 0; kg < 2; ++kg) {
            sfrA[kg] = (f32x4){0.f, 0.f, 0.f, 0.f};
            sfrB[kg] = (f32x4){0.f, 0.f, 0.f, 0.f};
        }
        #pragma unroll
        for (int kg = 0; kg < 2; ++kg)
            #pragma unroll
            for (int c = 0; c < 4; ++c)
                sfrB[kg] = __builtin_amdgcn_mfma_f32_16x16x32_bf16(
                    kf[kg][c], qfB[c], sfrB[kg], 0, 0, 0);
        if (aAct) {
            #pragma unroll
            for (int kg = 0; kg < 2; ++kg)
                #pragma unroll
                for (int c = 0; c < 4; ++c)
                    sfrA[kg] = __builtin_amdgcn_mfma_f32_16x16x32_bf16(
                        kf[kg][c], qfA[c], sfrA[kg], 0, 0, 0);
        }
        // prefetch next K tile into same regs (used next iter)
        if (kt + 1 < nk) {
            const int k1 = k0 + 32;
            #pragma unroll
            for (int kg = 0; kg < 2; ++kg)
                #pragma unroll
                for (int c = 0; c < 4; ++c)
                    kf[kg][c] = *reinterpret_cast<const bf16x8*>(
                        Kh + (size_t)(k1 + kg * 16 + lo) * HD + c * 32 + hi * 8);
        }
        // softmax + P staging
        if (aAct)
            softmax_group(sfrA, mA, lAcc, ofA, pbufA, qA0 + lo, k0, lo, hi);
        softmax_group(sfrB, mB, lBcc, ofB, pbufB, qB0 + lo, k0, lo, hi);
        // PV
        bf16x8 pfB = *reinterpret_cast<const bf16x8*>(pbufB + lane * 8);
        if (aAct) {
            bf16x8 pfA = *reinterpret_cast<const bf16x8*>(pbufA + lane * 8);
            #pragma unroll
            for (int n = 0; n < 8; ++n)
                ofA[n] = __builtin_amdgcn_mfma_f32_16x16x32_bf16(
                    pfA, vf[n], ofA[n], 0, 0, 0);
        }
        #pragma unroll
        for (int n = 0; n < 8; ++n)
            ofB[n] = __builtin_amdgcn_mfma_f32_16x16x32_bf16(
                pfB, vf[n], ofB[n], 0, 0, 0);
    }

    // epilogue: normalize + write (O rows back in C layout: q = hi*4+r)
    #pragma unroll
    for (int r = 0; r < 4; ++r) {
        float invA = 1.0f / __shfl(lAcc, hi * 4 + r);
        float invB = 1.0f / __shfl(lBcc, hi * 4 + r);
        bf16_t* dA = O + ((size_t)(b * SS + qA0 + hi * 4 + r)) * HID + h * HD;
        bf16_t* dB = O + ((size_t)(b * SS + qB0 + hi * 4 + r)) * HID + h * HD;
        #pragma unroll
        for (int n = 0; n < 8; ++n) {
            dA[n * 16 + lo] = (bf16_t)(ofA[n][r] * invA);
            dB[n * 16 + lo] = (bf16_t)(ofB[n][r] * invB);
        }
    }
}

// ---------------------------------------------------------------------------
extern "C" void kernel_launch(void* const* d_in, const int* in_sizes, int n_in,
                              void* d_out, int out_size, void* d_ws, size_t ws_size,
                              hipStream_t stream)
{
    const float* hidden = (const float*)d_in[0];
    const float* q_w    = (const float*)d_in[1];
    const float* q_b    = (const float*)d_in[2];
    const float* k_w    = (const float*)d_in[3];
    const float* k_b    = (const float*)d_in[4];
    const float* v_w    = (const float*)d_in[5];
    const float* v_b    = (const float*)d_in[6];
    const float* o_w    = (const float*)d_in[7];
    float* out = (float*)d_out;

    bf16_t* p  = (bf16_t*)d_ws;
    bf16_t* Xb = p; p += (size_t)4096 * 2048;
    bf16_t* Wq = p; p += (size_t)2048 * 2048;
    bf16_t* Wk = p; p += (size_t)512  * 2048;
    bf16_t* Wv = p; p += (size_t)512  * 2048;
    bf16_t* Wo = p; p += (size_t)2048 * 2048;
    bf16_t* Qb = p; p += (size_t)BB * NH  * SS * HD;
    bf16_t* Kb = p; p += (size_t)BB * NKV * SS * HD;
    bf16_t* Vt = p; p += (size_t)BB * NKV * HD * SS;
    bf16_t* Ab = p; p += (size_t)4096 * 2048;
    float2* rope_tab = (float2*)p;               // 2048*64 float2 = 1 MiB

    rope_tab_kernel<<<512, 256, 0, stream>>>(rope_tab);
    cast_hidden_kernel<<<4096, 256, 0, stream>>>(hidden, Xb);
    transpose_cast_kernel<<<dim3(64, 64, 4), 256, 0, stream>>>(
        q_w, k_w, v_w, o_w, Wq, Wk, Wv, Wo);
    qkv_gemm_kernel<<<dim3(24, 32), 256, 0, stream>>>(
        Xb, Wq, Wk, Wv, q_b, k_b, v_b, rope_tab, Qb, Kb, Vt);
    attn_kernel<<<512, 256, 0, stream>>>(Qb, Kb, Vt, Ab);
    oproj_gemm_kernel<<<dim3(16, 32), 256, 0, stream>>>(Ab, Wo, out);
}

// Round 5
// 337.949 us; speedup vs baseline: 8.5852x; 1.3543x over previous
//
#include <hip/hip_runtime.h>
#include <hip/hip_bf16.h>
#include <math.h>

#define BB 2
#define SS 2048
#define HID 2048
#define NH 16
#define NKV 4
#define HD 128

typedef __bf16 bf16_t;
typedef bf16_t bf16x8 __attribute__((ext_vector_type(8)));
typedef bf16_t bf16x4 __attribute__((ext_vector_type(4)));
typedef float f32x4 __attribute__((ext_vector_type(4)));

#define AS1 __attribute__((address_space(1)))
#define AS3 __attribute__((address_space(3)))

// softmax scale folded into Q at projection time: (1/sqrt(128)) * log2(e)
#define CSC 0.12746231410988061f

__device__ __forceinline__ void gload16(const bf16_t* g, bf16_t* lds) {
    __builtin_amdgcn_global_load_lds((const AS1 void*)g, (AS3 void*)lds, 16, 0, 0);
}

// ---------------------------------------------------------------------------
// Prep kernels
// ---------------------------------------------------------------------------
__global__ __launch_bounds__(256) void rope_tab_kernel(float2* __restrict__ tab)
{
    int i = blockIdx.x * 256 + threadIdx.x;       // s*64 + j, 131072 total
    int j = i & 63, s = i >> 6;
    float freq = expf(-(float)j * 0.14391156831212787f);  // ln(10000)/64
    float sn, cs;
    sincosf((float)s * freq, &sn, &cs);
    tab[i] = make_float2(cs, sn);
}

__global__ __launch_bounds__(256) void cast_hidden_kernel(
    const float* __restrict__ X, bf16_t* __restrict__ Xb)
{
    size_t i = (size_t)(blockIdx.x * 256 + threadIdx.x) * 8;
    float4 a = *reinterpret_cast<const float4*>(X + i);
    float4 b = *reinterpret_cast<const float4*>(X + i + 4);
    bf16x8 v = { (bf16_t)a.x, (bf16_t)a.y, (bf16_t)a.z, (bf16_t)a.w,
                 (bf16_t)b.x, (bf16_t)b.y, (bf16_t)b.z, (bf16_t)b.w };
    *reinterpret_cast<bf16x8*>(Xb + i) = v;
}

// W [K=2048][N] fp32 -> Wt [N][2048] bf16, tiled 32x32 via LDS
__global__ __launch_bounds__(256) void transpose_cast_kernel(
    const float* __restrict__ q_w, const float* __restrict__ k_w,
    const float* __restrict__ v_w, const float* __restrict__ o_w,
    bf16_t* __restrict__ Wq, bf16_t* __restrict__ Wk,
    bf16_t* __restrict__ Wv, bf16_t* __restrict__ Wo)
{
    __shared__ float tile[32][33];
    const float* W; bf16_t* Wt; int N;
    switch (blockIdx.z) {
        case 0: W = q_w; Wt = Wq; N = 2048; break;
        case 1: W = k_w; Wt = Wk; N = 512;  break;
        case 2: W = v_w; Wt = Wv; N = 512;  break;
        default: W = o_w; Wt = Wo; N = 2048; break;
    }
    int n0 = blockIdx.x * 32, k0 = blockIdx.y * 32;
    if (n0 >= N) return;
    int c = threadIdx.x & 31, r0 = threadIdx.x >> 5;   // 8 rows/pass
    #pragma unroll
    for (int rr = 0; rr < 32; rr += 8)
        tile[r0 + rr][c] = W[(size_t)(k0 + r0 + rr) * N + n0 + c];
    __syncthreads();
    #pragma unroll
    for (int rr = 0; rr < 32; rr += 8)
        Wt[(size_t)(n0 + r0 + rr) * HID + k0 + c] = (bf16_t)tile[c][r0 + rr];
}

// ---------------------------------------------------------------------------
// bf16 MFMA GEMM core: 128x128 tile, BK=32, 4 waves (2x2), 16x16x32 MFMA.
// ---------------------------------------------------------------------------
__device__ __forceinline__ void gemm_core_bf16(
    const bf16_t* __restrict__ A, const bf16_t* __restrict__ Bt,
    int m0, int n0, bf16_t* As, bf16_t* Bs, f32x4 acc[4][4])
{
    const int t = threadIdx.x;
    const int w = t >> 6, lane = t & 63, lo = lane & 15, hi = lane >> 4;
    const int wr = (w >> 1) * 64, wc = (w & 1) * 64;

    for (int k0 = 0; k0 < HID; k0 += 32) {
        __syncthreads();
        #pragma unroll
        for (int i = 0; i < 2; ++i) {
            int j = t + i * 256;                    // 16B chunk index 0..511
            gload16(A  + (size_t)(m0 + (j >> 2)) * HID + k0 + (j & 3) * 8,
                    As + (size_t)(w * 64 + i * 256) * 8);
            gload16(Bt + (size_t)(n0 + (j >> 2)) * HID + k0 + (j & 3) * 8,
                    Bs + (size_t)(w * 64 + i * 256) * 8);
        }
        __syncthreads();
        const bf16x8* Av = reinterpret_cast<const bf16x8*>(As);
        const bf16x8* Bv = reinterpret_cast<const bf16x8*>(Bs);
        bf16x8 a[4], b[4];
        #pragma unroll
        for (int m = 0; m < 4; ++m) a[m] = Av[(wr + m * 16 + lo) * 4 + hi];
        #pragma unroll
        for (int n = 0; n < 4; ++n) b[n] = Bv[(wc + n * 16 + lo) * 4 + hi];
        #pragma unroll
        for (int m = 0; m < 4; ++m)
            #pragma unroll
            for (int n = 0; n < 4; ++n)
                acc[m][n] = __builtin_amdgcn_mfma_f32_16x16x32_bf16(
                    a[m], b[n], acc[m][n], 0, 0, 0);
    }
}

// ---------------------------------------------------------------------------
// Fused QKV projection + bias + RoPE + layout shuffle.
// Q additionally pre-scaled by CSC (softmax scale in log2 domain).
// ---------------------------------------------------------------------------
__global__ __launch_bounds__(256) void qkv_gemm_kernel(
    const bf16_t* __restrict__ X,
    const bf16_t* __restrict__ Wq, const bf16_t* __restrict__ Wk,
    const bf16_t* __restrict__ Wv,
    const float* __restrict__ qb, const float* __restrict__ kb,
    const float* __restrict__ vb,
    const float2* __restrict__ rope_tab,
    bf16_t* __restrict__ Qo, bf16_t* __restrict__ Ko, bf16_t* __restrict__ Vt)
{
    __shared__ bf16_t As[128 * 32], Bs[128 * 32];
    f32x4 acc[4][4];
    #pragma unroll
    for (int m = 0; m < 4; ++m)
        #pragma unroll
        for (int n = 0; n < 4; ++n) acc[m][n] = (f32x4){0.f, 0.f, 0.f, 0.f};

    const int bn = blockIdx.x, m0 = blockIdx.y * 128;
    const bf16_t* Bt; const float* bias; int mode, head;
    if (bn < 16)      { Bt = Wq; bias = qb; mode = 0; head = bn; }
    else if (bn < 20) { Bt = Wk; bias = kb; mode = 1; head = bn - 16; }
    else              { Bt = Wv; bias = vb; mode = 2; head = bn - 20; }

    gemm_core_bf16(X, Bt, m0, head * 128, As, Bs, acc);

    const int t = threadIdx.x, w = t >> 6, lane = t & 63;
    const int lo = lane & 15, hi = lane >> 4;
    const int wr = (w >> 1) * 64, wc = (w & 1) * 64;

    #pragma unroll
    for (int n = 0; n < 4; ++n) {
        const int d = wc + n * 16 + lo;              // 0..127 within head
        const float bv = bias[head * 128 + d];
        const int jj = d >> 1;
        #pragma unroll
        for (int m = 0; m < 4; ++m) {
            #pragma unroll
            for (int r = 0; r < 4; ++r) {
                const int row = m0 + wr + m * 16 + hi * 4 + r;   // b*S + s
                const int b = row >> 11, s = row & 2047;
                float v = acc[m][n][r] + bv;
                if (mode < 2) {
                    float2 cs = rope_tab[s * 64 + jj];
                    float p = __shfl_xor(v, 1);
                    v = (d & 1) ? (p * cs.y + v * cs.x)
                                : (v * cs.x - p * cs.y);
                    if (mode == 0)
                        Qo[((size_t)(b * NH + head) * SS + s) * HD + d] =
                            (bf16_t)(v * CSC);
                    else
                        Ko[((size_t)(b * NKV + head) * SS + s) * HD + d] = (bf16_t)v;
                } else {
                    Vt[((size_t)(b * NKV + head) * HD + d) * SS + s] = (bf16_t)v;
                }
            }
        }
    }
}

// ---------------------------------------------------------------------------
// Output projection
// ---------------------------------------------------------------------------
__global__ __launch_bounds__(256) void oproj_gemm_kernel(
    const bf16_t* __restrict__ Ab, const bf16_t* __restrict__ Wo,
    float* __restrict__ out)
{
    __shared__ bf16_t As[128 * 32], Bs[128 * 32];
    f32x4 acc[4][4];
    #pragma unroll
    for (int m = 0; m < 4; ++m)
        #pragma unroll
        for (int n = 0; n < 4; ++n) acc[m][n] = (f32x4){0.f, 0.f, 0.f, 0.f};

    const int m0 = blockIdx.y * 128, n0 = blockIdx.x * 128;
    gemm_core_bf16(Ab, Wo, m0, n0, As, Bs, acc);

    const int t = threadIdx.x, w = t >> 6, lane = t & 63;
    const int lo = lane & 15, hi = lane >> 4;
    const int wr = (w >> 1) * 64, wc = (w & 1) * 64;
    #pragma unroll
    for (int m = 0; m < 4; ++m)
        #pragma unroll
        for (int n = 0; n < 4; ++n)
            #pragma unroll
            for (int r = 0; r < 4; ++r) {
                int row = m0 + wr + m * 16 + hi * 4 + r;
                int col = n0 + wc + n * 16 + lo;
                out[(size_t)row * HID + col] = acc[m][n][r];
            }
}

// ---------------------------------------------------------------------------
// MFMA flash attention v3: single stream/wave, block-shared LDS K/V staging,
// 4 waves/SIMD occupancy, descending-cost block order.
// Block = 4 waves = one 64-row q-supertile; grid = 1024 blocks.
// K tile [32 keys][128 d] (16B-slot XOR swizzle row&7);
// V tile [128 d][32 keys] (16B-slot XOR swizzle (d^(d>>2))&3).
// ---------------------------------------------------------------------------
__global__ __launch_bounds__(256, 4) void attn_kernel(
    const bf16_t* __restrict__ Q, const bf16_t* __restrict__ K,
    const bf16_t* __restrict__ Vt, bf16_t* __restrict__ O)
{
    __shared__ bf16_t Kbuf[2][4096];     // 16 KB
    __shared__ bf16_t Vbuf[2][4096];     // 16 KB
    __shared__ bf16_t Ps[4][512];        // 4 KB per-wave P staging

    const int t = threadIdx.x, w = t >> 6, lane = t & 63;
    const int lo = lane & 15, hi = lane >> 4;
    const int bid = blockIdx.x;
    const int b    = (bid >> 2) & 1, hkv = bid & 3;    // bid&7 -> XCD-local
    const int h    = hkv * 4 + ((bid >> 3) & 3);
    const int ss   = 31 - (bid >> 5);                  // descending cost
    const int q0   = ss * 64 + w * 16;
    const int dX   = (q0 + 15) >> 5;                   // diagonal (masked) tile
    const int nk   = 2 * ss + 2;

    const bf16_t* Qh = Q  + (size_t)(b * NH  + h)   * SS * HD;
    const bf16_t* Kh = K  + (size_t)(b * NKV + hkv) * SS * HD;
    const bf16_t* Vh = Vt + (size_t)(b * NKV + hkv) * HD * SS;

    // staging source precompute (inverse-swizzled global chunks)
    int preK[2], preV[2];
    #pragma unroll
    for (int i = 0; i < 2; ++i) {
        const int o = t + i * 256;                 // 16B chunk in tile
        const int krow = o >> 4;
        const int kslot = (o & 15) ^ (krow & 7);
        preK[i] = krow * HD + kslot * 8;
        const int d = o >> 2;
        const int cc = (o & 3) ^ ((d ^ (d >> 2)) & 3);
        preV[i] = d * SS + cc * 8;
    }

    // Q fragments (already scaled by CSC)
    bf16x8 qf[4];
    #pragma unroll
    for (int c = 0; c < 4; ++c)
        qf[c] = *reinterpret_cast<const bf16x8*>(
            Qh + (size_t)(q0 + lo) * HD + c * 32 + hi * 8);

    f32x4 of[8];
    #pragma unroll
    for (int n = 0; n < 8; ++n) of[n] = (f32x4){0.f, 0.f, 0.f, 0.f};
    float m_run = -3.0e38f, l_run = 0.f;

    // prologue: stage tile 0 into buffer 0
    #pragma unroll
    for (int i = 0; i < 2; ++i) {
        gload16(Kh + preK[i], &Kbuf[0][(w * 64 + i * 256) * 8]);
        gload16(Vh + preV[i], &Vbuf[0][(w * 64 + i * 256) * 8]);
    }

    for (int kt = 0; kt < nk; ++kt) {
        const int cur = kt & 1;
        __syncthreads();                 // staged buf[cur] complete (vmcnt drain)
        if (kt + 1 < nk) {               // issue next tile into buf[cur^1]
            const int kOff = (kt + 1) * 32 * HD;
            const int vOff = (kt + 1) * 32;
            #pragma unroll
            for (int i = 0; i < 2; ++i) {
                gload16(Kh + kOff + preK[i], &Kbuf[cur ^ 1][(w * 64 + i * 256) * 8]);
                gload16(Vh + vOff + preV[i], &Vbuf[cur ^ 1][(w * 64 + i * 256) * 8]);
            }
        }
        if (kt > dX) continue;           // retired wave: staging + barriers only

        // QK^T (swapped): C[key][q], q = lo lane-local
        const bf16_t* Kb = Kbuf[cur];
        f32x4 sfr[2];
        sfr[0] = (f32x4){0.f, 0.f, 0.f, 0.f};
        sfr[1] = (f32x4){0.f, 0.f, 0.f, 0.f};
        #pragma unroll
        for (int kg = 0; kg < 2; ++kg) {
            const int krow = kg * 16 + lo;
            #pragma unroll
            for (int c = 0; c < 4; ++c) {
                const int slot = (c * 4 + hi) ^ (krow & 7);
                bf16x8 kf = *reinterpret_cast<const bf16x8*>(
                    Kb + krow * 128 + slot * 8);
                sfr[kg] = __builtin_amdgcn_mfma_f32_16x16x32_bf16(
                    kf, qf[c], sfr[kg], 0, 0, 0);
            }
        }

        // softmax (log2 domain; scores pre-scaled via Q)
        float s[8];
        #pragma unroll
        for (int kg = 0; kg < 2; ++kg)
            #pragma unroll
            for (int r = 0; r < 4; ++r) s[kg * 4 + r] = sfr[kg][r];
        if (kt == dX) {                  // only diagonal tile needs masking
            const int qrow = q0 + lo;
            #pragma unroll
            for (int kg = 0; kg < 2; ++kg)
                #pragma unroll
                for (int r = 0; r < 4; ++r)
                    if (kt * 32 + kg * 16 + hi * 4 + r > qrow)
                        s[kg * 4 + r] = -3.0e38f;
        }
        float pmax = fmaxf(fmaxf(fmaxf(s[0], s[1]), fmaxf(s[2], s[3])),
                           fmaxf(fmaxf(s[4], s[5]), fmaxf(s[6], s[7])));
        pmax = fmaxf(pmax, __shfl_xor(pmax, 16));
        pmax = fmaxf(pmax, __shfl_xor(pmax, 32));
        if (!__all(pmax - m_run <= 11.5f)) {      // defer-max (T13)
            float mnew = fmaxf(m_run, pmax);
            float corr = exp2f(m_run - mnew);
            m_run = mnew;
            l_run *= corr;
            #pragma unroll
            for (int r = 0; r < 4; ++r) {
                float cr = __shfl(corr, hi * 4 + r);
                #pragma unroll
                for (int n = 0; n < 8; ++n) of[n][r] *= cr;
            }
        }
        float e[8], psl = 0.f;
        #pragma unroll
        for (int i = 0; i < 8; ++i) {
            e[i] = exp2f(s[i] - m_run);
            psl += e[i];
        }
        l_run += psl;                    // per-lane partial; reduced in epilogue

        // P -> LDS (A-frag gather order) -> fragment
        bf16_t* ps = Ps[w];
        #pragma unroll
        for (int kg = 0; kg < 2; ++kg) {
            bf16x4 pk;
            #pragma unroll
            for (int r = 0; r < 4; ++r) pk[r] = (bf16_t)e[kg * 4 + r];
            const int oct = kg * 2 + (hi >> 1);
            *reinterpret_cast<bf16x4*>(ps + (oct * 16 + lo) * 8 + (hi & 1) * 4) = pk;
        }
        bf16x8 pf = *reinterpret_cast<const bf16x8*>(ps + lane * 8);

        // PV from swizzled V tile
        const bf16_t* Vb = Vbuf[cur];
        #pragma unroll
        for (int n = 0; n < 8; ++n) {
            const int d = n * 16 + lo;
            const int cc = hi ^ ((d ^ (d >> 2)) & 3);
            bf16x8 vf = *reinterpret_cast<const bf16x8*>(Vb + d * 32 + cc * 8);
            of[n] = __builtin_amdgcn_mfma_f32_16x16x32_bf16(
                pf, vf, of[n], 0, 0, 0);
        }
    }

    // epilogue: reduce l across hi-replicas, normalize, write
    float lr = l_run + __shfl_xor(l_run, 16);
    lr += __shfl_xor(lr, 32);
    #pragma unroll
    for (int r = 0; r < 4; ++r) {
        float inv = 1.0f / __shfl(lr, hi * 4 + r);
        bf16_t* dst = O + ((size_t)(b * SS + q0 + hi * 4 + r)) * HID + h * HD;
        #pragma unroll
        for (int n = 0; n < 8; ++n)
            dst[n * 16 + lo] = (bf16_t)(of[n][r] * inv);
    }
}

// ---------------------------------------------------------------------------
extern "C" void kernel_launch(void* const* d_in, const int* in_sizes, int n_in,
                              void* d_out, int out_size, void* d_ws, size_t ws_size,
                              hipStream_t stream)
{
    const float* hidden = (const float*)d_in[0];
    const float* q_w    = (const float*)d_in[1];
    const float* q_b    = (const float*)d_in[2];
    const float* k_w    = (const float*)d_in[3];
    const float* k_b    = (const float*)d_in[4];
    const float* v_w    = (const float*)d_in[5];
    const float* v_b    = (const float*)d_in[6];
    const float* o_w    = (const float*)d_in[7];
    float* out = (float*)d_out;

    bf16_t* p  = (bf16_t*)d_ws;
    bf16_t* Xb = p; p += (size_t)4096 * 2048;
    bf16_t* Wq = p; p += (size_t)2048 * 2048;
    bf16_t* Wk = p; p += (size_t)512  * 2048;
    bf16_t* Wv = p; p += (size_t)512  * 2048;
    bf16_t* Wo = p; p += (size_t)2048 * 2048;
    bf16_t* Qb = p; p += (size_t)BB * NH  * SS * HD;
    bf16_t* Kb = p; p += (size_t)BB * NKV * SS * HD;
    bf16_t* Vt = p; p += (size_t)BB * NKV * HD * SS;
    bf16_t* Ab = p; p += (size_t)4096 * 2048;
    float2* rope_tab = (float2*)p;               // 2048*64 float2 = 1 MiB

    rope_tab_kernel<<<512, 256, 0, stream>>>(rope_tab);
    cast_hidden_kernel<<<4096, 256, 0, stream>>>(hidden, Xb);
    transpose_cast_kernel<<<dim3(64, 64, 4), 256, 0, stream>>>(
        q_w, k_w, v_w, o_w, Wq, Wk, Wv, Wo);
    qkv_gemm_kernel<<<dim3(24, 32), 256, 0, stream>>>(
        Xb, Wq, Wk, Wv, q_b, k_b, v_b, rope_tab, Qb, Kb, Vt);
    attn_kernel<<<1024, 256, 0, stream>>>(Qb, Kb, Vt, Ab);
    oproj_gemm_kernel<<<dim3(16, 32), 256, 0, stream>>>(Ab, Wo, out);
}